// Round 6
// baseline (259.703 us; speedup 1.0000x reference)
//
#include <hip/hip_runtime.h>
#include <hip/hip_bf16.h>

// Problem constants
#define BATCH 16
#define CH    512
#define NPIX  1024
#define GRP   32
#define CPG   16

typedef __attribute__((ext_vector_type(8))) short bf16x8;
typedef __attribute__((ext_vector_type(4))) float f32x4;

__device__ __forceinline__ ushort f2b(float f) {
    union { float f; unsigned u; } v; v.f = f;
    unsigned u = v.u;
    u += 0x7FFF + ((u >> 16) & 1);   // round-to-nearest-even
    return (ushort)(u >> 16);
}

// async global->LDS, 16B per lane. LDS dest must be wave-uniform base + lane*16.
#define GLD16(gp, lp) __builtin_amdgcn_global_load_lds( \
    (__attribute__((address_space(1))) void*)(gp), \
    (__attribute__((address_space(3))) void*)(lp), 16, 0, 0)

// ---------------- weight conversion f32 -> bf16  (+ rowsum zero) ----------------
__global__ __launch_bounds__(256) void convert_weights(
    const float* __restrict__ wq, const float* __restrict__ wp,
    ushort* __restrict__ wq_b, ushort* __restrict__ wp_b,
    float* __restrict__ rowsum) {
    int i = blockIdx.x * 256 + threadIdx.x;   // 1048576 total
    if (i < 786432) wq_b[i] = f2b(wq[i]);
    else            wp_b[i - 786432] = f2b(wp[i - 786432]);
    if (i < BATCH * NPIX) rowsum[i] = 0.f;    // 16384 floats
}

// ---------------- GroupNorm stats ----------------
__global__ __launch_bounds__(256) void gn_stats(
    const float* __restrict__ x, float* __restrict__ mu, float* __restrict__ rs) {
    int g = blockIdx.x, b = blockIdx.y;
    const float4* p = (const float4*)(x + ((size_t)b * CH + g * CPG) * NPIX); // 16384 contiguous
    float s = 0.f, ss = 0.f;
    for (int i = threadIdx.x; i < 4096; i += 256) {
        float4 v = p[i];
        s  += v.x + v.y + v.z + v.w;
        ss += v.x*v.x + v.y*v.y + v.z*v.z + v.w*v.w;
    }
    for (int o = 1; o < 64; o <<= 1) { s += __shfl_xor(s, o); ss += __shfl_xor(ss, o); }
    __shared__ float as[4], bs[4];
    int w = threadIdx.x >> 6;
    if ((threadIdx.x & 63) == 0) { as[w] = s; bs[w] = ss; }
    __syncthreads();
    if (threadIdx.x == 0) {
        s  = as[0] + as[1] + as[2] + as[3];
        ss = bs[0] + bs[1] + bs[2] + bs[3];
        float m = s * (1.0f / 16384.0f);
        float var = ss * (1.0f / 16384.0f) - m * m;
        mu[b * GRP + g] = m;
        rs[b * GRP + g] = rsqrtf(var + 1e-5f);
    }
}

// ---------------- GroupNorm normalize + LDS-transposed coalesced write ----------------
__global__ __launch_bounds__(256) void gn_norm_t(
    const float* __restrict__ x, const float* __restrict__ mu, const float* __restrict__ rs,
    const float* __restrict__ gamma, const float* __restrict__ beta, ushort* __restrict__ hT) {
    int c0 = blockIdx.x * 32, n0 = blockIdx.y * 128, b = blockIdx.z;
    __shared__ ushort t[128 * 32];
    int tid = threadIdx.x;
#pragma unroll
    for (int i = 0; i < 4; i++) {
        int f = tid + i * 256;          // 1024 float4 chunks: c in [0,32), nf in [0,32)
        int c = f >> 5, nf = f & 31;
        int cg = c0 + c;
        float m = mu[b * GRP + (cg >> 4)], r = rs[b * GRP + (cg >> 4)];
        float ga = gamma[cg] * r;
        float be = beta[cg] - m * ga;
        float4 v = *(const float4*)(x + ((size_t)(b * CH + cg)) * NPIX + n0 + nf * 4);
        float vv[4] = {v.x, v.y, v.z, v.w};
#pragma unroll
        for (int j = 0; j < 4; j++) {
            int n = nf * 4 + j;
            int pos = (c >> 3) ^ ((n >> 2) & 3);
            t[n * 32 + pos * 8 + (c & 7)] = f2b(vv[j] * ga + be);
        }
    }
    __syncthreads();
#pragma unroll
    for (int i = 0; i < 2; i++) {
        int ch = tid + i * 256;         // 512 chunks: n in [0,128), g in [0,4)
        int n = ch >> 2, g = ch & 3;
        int pos = g ^ ((n >> 2) & 3);
        uint4 val = *(const uint4*)&t[n * 32 + pos * 8];
        *(uint4*)(hT + ((size_t)b * NPIX + n0 + n) * CH + c0 + g * 8) = val;
    }
}

// ---------------- generic bf16 gemm_bt: C[m][n] = sum_k A[m][k] * Bt[n][k] ----------------
// DOUBLE-BUFFERED BK=32: total LDS 32 KB (same as R4 single-buf BK=64) -> keeps
// 4 blocks/CU, AND stage(t+1) issues a full compute-phase before its barrier
// drain -> both inter-block and intra-block latency hiding.
// Swizzle for 64B rows: granule g of row r stored at pos g^((r>>1)&3); staging
// lane-contiguous, frag ds_read_b128 exactly 2-way (free, m136).
// EPI 0: qkv  (bias by col n; n<1024 -> qk[m*1024+n] bf16; n>=1024 -> v[(n-1024)*1024+m] bf16)
// EPI 1: u = exp(s*scale) bf16 + atomic f32 row-sums (max-free softmax numerator)
// EPI 2: O1T bf16, divided by rowsum[m]
// EPI 3: out  (f32, + bias[m] + resid)
#define BM 128
#define BN 128
#define BK 32
#define ABUF (BM * BK)
#define BBUF (BN * BK)

template<int EPI>
__global__ __launch_bounds__(256, 4) void gemm_bt(
    const ushort* __restrict__ A, long sA, int lda,
    const ushort* __restrict__ Bt, long sB, int ldb,
    int M, int N, int K,
    void* __restrict__ Out, long sO, int ldo,
    const float* __restrict__ bias,
    const float* __restrict__ resid,
    ushort* __restrict__ vout,
    float* __restrict__ rowsum,
    float scale) {
    __shared__ __align__(16) ushort As[2 * ABUF];   // 2 x 8 KB
    __shared__ __align__(16) ushort Bs[2 * BBUF];   // 2 x 8 KB
    int b = blockIdx.z;
    A  += (size_t)b * sA;
    Bt += (size_t)b * sB;
    int m0 = blockIdx.y * BM, n0 = blockIdx.x * BN;
    int tid = threadIdx.x;
    int lane = tid & 63;
    int wave = tid >> 6;
    int q = lane >> 4, l = lane & 15;
    int wm = (wave >> 1) * 64, wn = (wave & 1) * 64;

    // staging granules: p in [0,512) per matrix; r=p>>2, stored pos j=p&3 holds
    // global granule g=j^((r>>1)&3). Thread handles p = tid + i*256, i=0..1.
    int aoff[2], boff[2], lof[2];
#pragma unroll
    for (int i = 0; i < 2; i++) {
        int p = tid + i * 256, r = p >> 2, g = (p & 3) ^ ((r >> 1) & 3);
        aoff[i] = (m0 + r) * lda + g * 8;
        boff[i] = (n0 + r) * ldb + g * 8;
        lof[i] = p * 8;
    }

    // frag offsets: row r, granule q stored at pos q^((r>>1)&3); row stride 32 elems
    int offA[4], offB[4];
#pragma unroll
    for (int mi = 0; mi < 4; mi++) {
        int r = wm + mi * 16 + l;
        offA[mi] = r * 32 + ((q ^ ((r >> 1) & 3)) * 8);
    }
#pragma unroll
    for (int ni = 0; ni < 4; ni++) {
        int r = wn + ni * 16 + l;
        offB[ni] = r * 32 + ((q ^ ((r >> 1) & 3)) * 8);
    }

    f32x4 zero = {0.f, 0.f, 0.f, 0.f};
    f32x4 acc[4][4];
#pragma unroll
    for (int mi = 0; mi < 4; mi++)
#pragma unroll
        for (int ni = 0; ni < 4; ni++) acc[mi][ni] = zero;

    // prologue: stage k=0 into buffer 0
#pragma unroll
    for (int i = 0; i < 2; i++) GLD16(A + aoff[i], As + lof[i]);
#pragma unroll
    for (int i = 0; i < 2; i++) GLD16(Bt + boff[i], Bs + lof[i]);

    int nb = 0;
    for (int k0 = 0; k0 < K; k0 += BK) {
        __syncthreads();   // drains stage(k0) — issued one compute-phase ago
        if (k0 + BK < K) {
            int xb = (nb ^ 1);
#pragma unroll
            for (int i = 0; i < 2; i++) GLD16(A + aoff[i] + k0 + BK, As + xb * ABUF + lof[i]);
#pragma unroll
            for (int i = 0; i < 2; i++) GLD16(Bt + boff[i] + k0 + BK, Bs + xb * BBUF + lof[i]);
        }
        const ushort* Ab = As + nb * ABUF;
        const ushort* Bb = Bs + nb * BBUF;
        bf16x8 af[4], bfr[4];
#pragma unroll
        for (int mi = 0; mi < 4; mi++) af[mi]  = *(const bf16x8*)(Ab + offA[mi]);
#pragma unroll
        for (int ni = 0; ni < 4; ni++) bfr[ni] = *(const bf16x8*)(Bb + offB[ni]);
#pragma unroll
        for (int mi = 0; mi < 4; mi++)
#pragma unroll
            for (int ni = 0; ni < 4; ni++)
                acc[mi][ni] = __builtin_amdgcn_mfma_f32_16x16x32_bf16(
                    af[mi], bfr[ni], acc[mi][ni], 0, 0, 0);
        nb ^= 1;
    }

    // epilogue; C/D frag: row m = q*4+reg, col n = l (m89-verified mapping)
    if (EPI == 1) {
        // u = exp(s*scale), bf16 store + atomic row sums
#pragma unroll
        for (int mi = 0; mi < 4; mi++) {
            float rsum[4] = {0.f, 0.f, 0.f, 0.f};
#pragma unroll
            for (int ni = 0; ni < 4; ni++) {
                int n = n0 + wn + ni * 16 + l;
#pragma unroll
                for (int rg = 0; rg < 4; rg++) {
                    int m = m0 + wm + mi * 16 + q * 4 + rg;
                    float u = __expf(acc[mi][ni][rg] * scale);
                    rsum[rg] += u;
                    ((ushort*)Out)[(size_t)b * sO + (size_t)m * ldo + n] = f2b(u);
                }
            }
#pragma unroll
            for (int rg = 0; rg < 4; rg++) {
                float s = rsum[rg];
                s += __shfl_xor(s, 1); s += __shfl_xor(s, 2);
                s += __shfl_xor(s, 4); s += __shfl_xor(s, 8);
                if (l == 0)
                    atomicAdd(&rowsum[b * NPIX + m0 + wm + mi * 16 + q * 4 + rg], s);
            }
        }
        return;
    }
#pragma unroll
    for (int mi = 0; mi < 4; mi++) {
        float inv[4];
        if (EPI == 2) {
#pragma unroll
            for (int rg = 0; rg < 4; rg++)
                inv[rg] = 1.0f / rowsum[b * NPIX + m0 + wm + mi * 16 + q * 4 + rg];
        }
#pragma unroll
        for (int ni = 0; ni < 4; ni++) {
            int mbase = m0 + wm + mi * 16 + q * 4;
            int n = n0 + wn + ni * 16 + l;
#pragma unroll
            for (int rg = 0; rg < 4; rg++) {
                int m = mbase + rg;
                float v = acc[mi][ni][rg];
                if (EPI == 0) {
                    v += bias[n];
                    if (n < 1024)
                        ((ushort*)Out)[(size_t)b * sO + (size_t)m * ldo + n] = f2b(v);
                    else
                        vout[(size_t)b * (512 * 1024) + (size_t)(n - 1024) * 1024 + m] = f2b(v);
                } else if (EPI == 2) {
                    ((ushort*)Out)[(size_t)b * sO + (size_t)m * ldo + n] = f2b(v * inv[rg]);
                } else {
                    v += bias[m] + resid[(size_t)b * sO + (size_t)m * ldo + n];
                    ((float*)Out)[(size_t)b * sO + (size_t)m * ldo + n] = v;
                }
            }
        }
    }
}

extern "C" void kernel_launch(void* const* d_in, const int* in_sizes, int n_in,
                              void* d_out, int out_size, void* d_ws, size_t ws_size,
                              hipStream_t stream) {
    const float* x     = (const float*)d_in[0];
    const float* gamma = (const float*)d_in[1];
    const float* beta  = (const float*)d_in[2];
    const float* wqkv  = (const float*)d_in[3];
    const float* bqkv  = (const float*)d_in[4];
    const float* wproj = (const float*)d_in[5];
    const float* bproj = (const float*)d_in[6];
    float* out = (float*)d_out;
    char* ws = (char*)d_ws;

    // workspace layout (bytes); total ~101 MB
    ushort* wq_b   = (ushort*)(ws + 0);          // 1.5 MB
    ushort* wp_b   = (ushort*)(ws + 1572864);    // 0.5 MB
    float*  mu     = (float*)(ws + 2097152);     // 2 KB
    float*  rs     = (float*)(ws + 2099200);     // 2 KB
    float*  rowsum = (float*)(ws + 2101248);     // 64 KB [b][i]
    ushort* hT     = (ushort*)(ws + 2166784);    // 16 MB [b][n][c]  (reused as O1T)
    ushort* qk     = (ushort*)(ws + 18944000);   // 32 MB [b][n][q0..511,k512..1023]
    ushort* vb     = (ushort*)(ws + 52498432);   // 16 MB [b][c][j]
    ushort* u      = (ushort*)(ws + 69275648);   // 32 MB [b][i][j]  exp(s) bf16
    ushort* O1T    = hT;                          // alias: hT dead after MM1

    convert_weights<<<4096, 256, 0, stream>>>(wqkv, wproj, wq_b, wp_b, rowsum);
    gn_stats<<<dim3(GRP, BATCH), 256, 0, stream>>>(x, mu, rs);
    gn_norm_t<<<dim3(16, 8, BATCH), 256, 0, stream>>>(x, mu, rs, gamma, beta, hT);

    // MM1: qkvT[n][o] = sum_c hT[n][c] * Wqkv[o][c]  (M=1024, N=1536, K=512)
    gemm_bt<0><<<dim3(12, 8, BATCH), 256, 0, stream>>>(
        hT, 524288, 512, wq_b, 0, 512, 1024, 1536, 512,
        qk, 1048576, 1024, bqkv, nullptr, vb, nullptr, 0.f);

    // MM2: u[i][j] = exp(q.k * scale), rowsum[i] += ...  (M=N=1024, K=512)
    gemm_bt<1><<<dim3(8, 8, BATCH), 256, 0, stream>>>(
        qk, 1048576, 1024, qk + 512, 1048576, 1024, 1024, 1024, 512,
        u, 1048576, 1024, nullptr, nullptr, nullptr, rowsum, 0.044194173824159216f);

    // MM3: O1T[i][c] = (sum_j u[i][j] * v[c][j]) / rowsum[i]  (M=1024, N=512, K=1024)
    gemm_bt<2><<<dim3(4, 8, BATCH), 256, 0, stream>>>(
        u, 1048576, 1024, vb, 524288, 1024, 1024, 512, 1024,
        O1T, 524288, 512, nullptr, nullptr, nullptr, rowsum, 0.f);

    // MM4: out[o][n] = sum_c Wp[o][c] * O1T[n][c] + bproj[o] + x  (M=512, N=1024, K=512)
    gemm_bt<3><<<dim3(8, 4, BATCH), 256, 0, stream>>>(
        wp_b, 0, 512, O1T, 524288, 512, 512, 1024, 512,
        out, 524288, 1024, bproj, x, nullptr, nullptr, 0.f);
}

// Round 7
// 239.212 us; speedup vs baseline: 1.0857x; 1.0857x over previous
//
#include <hip/hip_runtime.h>
#include <hip/hip_bf16.h>

// Problem constants
#define BATCH 16
#define CH    512
#define NPIX  1024
#define GRP   32
#define CPG   16

typedef __attribute__((ext_vector_type(8))) short bf16x8;
typedef __attribute__((ext_vector_type(4))) float f32x4;

__device__ __forceinline__ ushort f2b(float f) {
    union { float f; unsigned u; } v; v.f = f;
    unsigned u = v.u;
    u += 0x7FFF + ((u >> 16) & 1);   // round-to-nearest-even
    return (ushort)(u >> 16);
}

// async global->LDS, 16B per lane. LDS dest must be wave-uniform base + lane*16.
#define GLD16(gp, lp) __builtin_amdgcn_global_load_lds( \
    (__attribute__((address_space(1))) void*)(gp), \
    (__attribute__((address_space(3))) void*)(lp), 16, 0, 0)

// ---------------- weight conversion f32 -> bf16  (+ rowsum zero) ----------------
__global__ __launch_bounds__(256) void convert_weights(
    const float* __restrict__ wq, const float* __restrict__ wp,
    ushort* __restrict__ wq_b, ushort* __restrict__ wp_b,
    float* __restrict__ rowsum) {
    int i = blockIdx.x * 256 + threadIdx.x;   // 1048576 total
    if (i < 786432) wq_b[i] = f2b(wq[i]);
    else            wp_b[i - 786432] = f2b(wp[i - 786432]);
    if (i < BATCH * NPIX) rowsum[i] = 0.f;    // 16384 floats
}

// ---------------- GroupNorm stats ----------------
__global__ __launch_bounds__(256) void gn_stats(
    const float* __restrict__ x, float* __restrict__ mu, float* __restrict__ rs) {
    int g = blockIdx.x, b = blockIdx.y;
    const float4* p = (const float4*)(x + ((size_t)b * CH + g * CPG) * NPIX); // 16384 contiguous
    float s = 0.f, ss = 0.f;
    for (int i = threadIdx.x; i < 4096; i += 256) {
        float4 v = p[i];
        s  += v.x + v.y + v.z + v.w;
        ss += v.x*v.x + v.y*v.y + v.z*v.z + v.w*v.w;
    }
    for (int o = 1; o < 64; o <<= 1) { s += __shfl_xor(s, o); ss += __shfl_xor(ss, o); }
    __shared__ float as[4], bs[4];
    int w = threadIdx.x >> 6;
    if ((threadIdx.x & 63) == 0) { as[w] = s; bs[w] = ss; }
    __syncthreads();
    if (threadIdx.x == 0) {
        s  = as[0] + as[1] + as[2] + as[3];
        ss = bs[0] + bs[1] + bs[2] + bs[3];
        float m = s * (1.0f / 16384.0f);
        float var = ss * (1.0f / 16384.0f) - m * m;
        mu[b * GRP + g] = m;
        rs[b * GRP + g] = rsqrtf(var + 1e-5f);
    }
}

// ---------------- GroupNorm normalize + LDS-transposed coalesced write ----------------
__global__ __launch_bounds__(256) void gn_norm_t(
    const float* __restrict__ x, const float* __restrict__ mu, const float* __restrict__ rs,
    const float* __restrict__ gamma, const float* __restrict__ beta, ushort* __restrict__ hT) {
    int c0 = blockIdx.x * 32, n0 = blockIdx.y * 128, b = blockIdx.z;
    __shared__ ushort t[128 * 32];
    int tid = threadIdx.x;
#pragma unroll
    for (int i = 0; i < 4; i++) {
        int f = tid + i * 256;          // 1024 float4 chunks: c in [0,32), nf in [0,32)
        int c = f >> 5, nf = f & 31;
        int cg = c0 + c;
        float m = mu[b * GRP + (cg >> 4)], r = rs[b * GRP + (cg >> 4)];
        float ga = gamma[cg] * r;
        float be = beta[cg] - m * ga;
        float4 v = *(const float4*)(x + ((size_t)(b * CH + cg)) * NPIX + n0 + nf * 4);
        float vv[4] = {v.x, v.y, v.z, v.w};
#pragma unroll
        for (int j = 0; j < 4; j++) {
            int n = nf * 4 + j;
            int pos = (c >> 3) ^ ((n >> 2) & 3);
            t[n * 32 + pos * 8 + (c & 7)] = f2b(vv[j] * ga + be);
        }
    }
    __syncthreads();
#pragma unroll
    for (int i = 0; i < 2; i++) {
        int ch = tid + i * 256;         // 512 chunks: n in [0,128), g in [0,4)
        int n = ch >> 2, g = ch & 3;
        int pos = g ^ ((n >> 2) & 3);
        uint4 val = *(const uint4*)&t[n * 32 + pos * 8];
        *(uint4*)(hT + ((size_t)b * NPIX + n0 + n) * CH + c0 + g * 8) = val;
    }
}

// ---------------- generic bf16 gemm_bt<EPI,BM,BN>: C[m][n] = sum_k A[m][k]*Bt[n][k] --------
// R4 structure (best measured): single-buffered BK=64, global_load_lds width=16,
// XOR-swizzled LDS (granule g of row r at pos g^(r&7)); staging lane-contiguous,
// frag ds_read_b128 2-way-free. Waves tiled 2x2; wave tile (BM/2)x(BN/2).
// EPI 0: qkv. n0<1024 tiles: direct q/k store. n0>=1024 tiles: 128x128 LDS
//        transpose (reuses staging LDS) then coalesced 16B stores to v[c][j].
// EPI 1: u = exp(s*scale) bf16 + atomic f32 row-sums (max-free softmax numerator)
// EPI 2: O1T bf16, divided by rowsum[m]
// EPI 3: out  (f32, + bias[m] + resid)
#define BK 64

template<int EPI, int BMt, int BNt>
__global__ __launch_bounds__(256, 4) void gemm_bt(
    const ushort* __restrict__ A, long sA, int lda,
    const ushort* __restrict__ Bt, long sB, int ldb,
    int K,
    void* __restrict__ Out, long sO, int ldo,
    const float* __restrict__ bias,
    const float* __restrict__ resid,
    ushort* __restrict__ vout,
    float* __restrict__ rowsum,
    float scale) {
    constexpr int FM = BMt / 32;          // frag count in m per wave
    constexpr int FN = BNt / 32;          // frag count in n per wave
    constexpr int SA = BMt / 32;          // staging granules/thread for A (BMt*BK/8/256)
    constexpr int SB = BNt / 32;
    __shared__ __align__(16) ushort sh[(BMt + BNt) * BK];
    ushort* As = sh;
    ushort* Bs = sh + BMt * BK;
    int b = blockIdx.z;
    A  += (size_t)b * sA;
    Bt += (size_t)b * sB;
    int m0 = blockIdx.y * BMt, n0 = blockIdx.x * BNt;
    int tid = threadIdx.x;
    int lane = tid & 63;
    int wave = tid >> 6;
    int q = lane >> 4, l = lane & 15;
    int wm = (wave >> 1) * (BMt / 2), wn = (wave & 1) * (BNt / 2);

    // staging: granule p; r=p>>3, stored pos j=p&7 holds global granule g=j^(r&7)
    int aoff[SA], boff[SB], lofa[SA], lofb[SB];
#pragma unroll
    for (int i = 0; i < SA; i++) {
        int p = tid + i * 256, r = p >> 3, g = (p & 7) ^ (r & 7);
        aoff[i] = (m0 + r) * lda + g * 8;
        lofa[i] = p * 8;
    }
#pragma unroll
    for (int i = 0; i < SB; i++) {
        int p = tid + i * 256, r = p >> 3, g = (p & 7) ^ (r & 7);
        boff[i] = (n0 + r) * ldb + g * 8;
        lofb[i] = p * 8;
    }

    // frag offsets: row r, k-chunk kk: granule G=kk*4+q stored at G^(r&7)
    int offA[FM][2], offB[FN][2];
#pragma unroll
    for (int mi = 0; mi < FM; mi++) {
        int r = wm + mi * 16 + l;
#pragma unroll
        for (int kk = 0; kk < 2; kk++)
            offA[mi][kk] = r * 64 + ((((kk << 2) | q) ^ (r & 7)) * 8);
    }
#pragma unroll
    for (int ni = 0; ni < FN; ni++) {
        int r = wn + ni * 16 + l;
#pragma unroll
        for (int kk = 0; kk < 2; kk++)
            offB[ni][kk] = r * 64 + ((((kk << 2) | q) ^ (r & 7)) * 8);
    }

    f32x4 zero = {0.f, 0.f, 0.f, 0.f};
    f32x4 acc[FM][FN];
#pragma unroll
    for (int mi = 0; mi < FM; mi++)
#pragma unroll
        for (int ni = 0; ni < FN; ni++) acc[mi][ni] = zero;

    for (int k0 = 0; k0 < K; k0 += BK) {
        __syncthreads();
#pragma unroll
        for (int i = 0; i < SA; i++) GLD16(A + aoff[i] + k0, As + lofa[i]);
#pragma unroll
        for (int i = 0; i < SB; i++) GLD16(Bt + boff[i] + k0, Bs + lofb[i]);
        __syncthreads();
#pragma unroll
        for (int kk = 0; kk < 2; kk++) {
            bf16x8 af[FM], bfr[FN];
#pragma unroll
            for (int mi = 0; mi < FM; mi++) af[mi]  = *(const bf16x8*)(As + offA[mi][kk]);
#pragma unroll
            for (int ni = 0; ni < FN; ni++) bfr[ni] = *(const bf16x8*)(Bs + offB[ni][kk]);
#pragma unroll
            for (int mi = 0; mi < FM; mi++)
#pragma unroll
                for (int ni = 0; ni < FN; ni++)
                    acc[mi][ni] = __builtin_amdgcn_mfma_f32_16x16x32_bf16(
                        af[mi], bfr[ni], acc[mi][ni], 0, 0, 0);
        }
    }

    // epilogue; C/D frag: row m = q*4+reg, col n = l (m89-verified mapping)
    if (EPI == 0) {
        if (n0 >= 1024) {
            // pure-v tile: transpose via LDS (BMt*BNt*2 = 32 KB = staging LDS), then
            // coalesced 16B stores to vout[c=n-1024][j=m]. Swizzle: m-granule gm
            // stored at pos gm^(n&15).
            __syncthreads();   // staging LDS dead only after all waves' last kk
#pragma unroll
            for (int mi = 0; mi < FM; mi++)
#pragma unroll
                for (int ni = 0; ni < FN; ni++) {
                    int nl = wn + ni * 16 + l;
                    float bi = bias[n0 + nl];
#pragma unroll
                    for (int rg = 0; rg < 4; rg++) {
                        int ml = wm + mi * 16 + q * 4 + rg;
                        int pos = (ml >> 3) ^ (nl & 15);
                        sh[nl * 128 + pos * 8 + (ml & 7)] = f2b(acc[mi][ni][rg] + bi);
                    }
                }
            __syncthreads();
#pragma unroll
            for (int i = 0; i < 8; i++) {
                int idx = tid + i * 256;          // 2048 chunks: 128 rows x 16
                int nl = idx >> 4, ch = idx & 15;
                int g2 = ch ^ (nl & 15);
                uint4 val = *(const uint4*)&sh[nl * 128 + g2 * 8];
                *(uint4*)(vout + (size_t)b * (512 * 1024)
                          + (size_t)(n0 - 1024 + nl) * 1024 + m0 + ch * 8) = val;
            }
            return;
        }
        // pure q/k tile: direct stores
#pragma unroll
        for (int mi = 0; mi < FM; mi++)
#pragma unroll
            for (int ni = 0; ni < FN; ni++) {
                int n = n0 + wn + ni * 16 + l;
                float bi = bias[n];
#pragma unroll
                for (int rg = 0; rg < 4; rg++) {
                    int m = m0 + wm + mi * 16 + q * 4 + rg;
                    ((ushort*)Out)[(size_t)b * sO + (size_t)m * ldo + n] =
                        f2b(acc[mi][ni][rg] + bi);
                }
            }
        return;
    }
    if (EPI == 1) {
        // u = exp(s*scale), bf16 store + atomic row sums
#pragma unroll
        for (int mi = 0; mi < FM; mi++) {
            float rsum[4] = {0.f, 0.f, 0.f, 0.f};
#pragma unroll
            for (int ni = 0; ni < FN; ni++) {
                int n = n0 + wn + ni * 16 + l;
#pragma unroll
                for (int rg = 0; rg < 4; rg++) {
                    int m = m0 + wm + mi * 16 + q * 4 + rg;
                    float u = __expf(acc[mi][ni][rg] * scale);
                    rsum[rg] += u;
                    ((ushort*)Out)[(size_t)b * sO + (size_t)m * ldo + n] = f2b(u);
                }
            }
#pragma unroll
            for (int rg = 0; rg < 4; rg++) {
                float s = rsum[rg];
                s += __shfl_xor(s, 1); s += __shfl_xor(s, 2);
                s += __shfl_xor(s, 4); s += __shfl_xor(s, 8);
                if (l == 0)
                    atomicAdd(&rowsum[b * NPIX + m0 + wm + mi * 16 + q * 4 + rg], s);
            }
        }
        return;
    }
#pragma unroll
    for (int mi = 0; mi < FM; mi++) {
        float inv[4];
        if (EPI == 2) {
#pragma unroll
            for (int rg = 0; rg < 4; rg++)
                inv[rg] = 1.0f / rowsum[b * NPIX + m0 + wm + mi * 16 + q * 4 + rg];
        }
#pragma unroll
        for (int ni = 0; ni < FN; ni++) {
            int mbase = m0 + wm + mi * 16 + q * 4;
            int n = n0 + wn + ni * 16 + l;
#pragma unroll
            for (int rg = 0; rg < 4; rg++) {
                int m = mbase + rg;
                float v = acc[mi][ni][rg];
                if (EPI == 2) {
                    ((ushort*)Out)[(size_t)b * sO + (size_t)m * ldo + n] = f2b(v * inv[rg]);
                } else {
                    v += bias[m] + resid[(size_t)b * sO + (size_t)m * ldo + n];
                    ((float*)Out)[(size_t)b * sO + (size_t)m * ldo + n] = v;
                }
            }
        }
    }
}

extern "C" void kernel_launch(void* const* d_in, const int* in_sizes, int n_in,
                              void* d_out, int out_size, void* d_ws, size_t ws_size,
                              hipStream_t stream) {
    const float* x     = (const float*)d_in[0];
    const float* gamma = (const float*)d_in[1];
    const float* beta  = (const float*)d_in[2];
    const float* wqkv  = (const float*)d_in[3];
    const float* bqkv  = (const float*)d_in[4];
    const float* wproj = (const float*)d_in[5];
    const float* bproj = (const float*)d_in[6];
    float* out = (float*)d_out;
    char* ws = (char*)d_ws;

    // workspace layout (bytes); total ~101 MB
    ushort* wq_b   = (ushort*)(ws + 0);          // 1.5 MB
    ushort* wp_b   = (ushort*)(ws + 1572864);    // 0.5 MB
    float*  mu     = (float*)(ws + 2097152);     // 2 KB
    float*  rs     = (float*)(ws + 2099200);     // 2 KB
    float*  rowsum = (float*)(ws + 2101248);     // 64 KB [b][i]
    ushort* hT     = (ushort*)(ws + 2166784);    // 16 MB [b][n][c]  (reused as O1T)
    ushort* qk     = (ushort*)(ws + 18944000);   // 32 MB [b][n][q0..511,k512..1023]
    ushort* vb     = (ushort*)(ws + 52498432);   // 16 MB [b][c][j]
    ushort* u      = (ushort*)(ws + 69275648);   // 32 MB [b][i][j]  exp(s) bf16
    ushort* O1T    = hT;                          // alias: hT dead after MM1

    convert_weights<<<4096, 256, 0, stream>>>(wqkv, wproj, wq_b, wp_b, rowsum);
    gn_stats<<<dim3(GRP, BATCH), 256, 0, stream>>>(x, mu, rs);
    gn_norm_t<<<dim3(16, 8, BATCH), 256, 0, stream>>>(x, mu, rs, gamma, beta, hT);

    // MM1: qkvT[n][o] = sum_c hT[n][c] * Wqkv[o][c]  (M=1024, N=1536, K=512)
    gemm_bt<0, 128, 128><<<dim3(12, 8, BATCH), 256, 0, stream>>>(
        hT, 524288, 512, wq_b, 0, 512, 512,
        qk, 1048576, 1024, bqkv, nullptr, vb, nullptr, 0.f);

    // MM2: u[i][j] = exp(q.k * scale), rowsum[i] += ...  (M=N=1024, K=512)
    gemm_bt<1, 128, 128><<<dim3(8, 8, BATCH), 256, 0, stream>>>(
        qk, 1048576, 1024, qk + 512, 1048576, 1024, 512,
        u, 1048576, 1024, nullptr, nullptr, nullptr, rowsum, 0.044194173824159216f);

    // MM3: O1T[i][c] = (sum_j u[i][j] * v[c][j]) / rowsum[i]  (M=1024, N=512, K=1024)
    gemm_bt<2, 128, 64><<<dim3(8, 8, BATCH), 256, 0, stream>>>(
        u, 1048576, 1024, vb, 524288, 1024, 1024,
        O1T, 524288, 512, nullptr, nullptr, nullptr, rowsum, 0.f);

    // MM4: out[o][n] = sum_c Wp[o][c] * O1T[n][c] + bproj[o] + x  (M=512, N=1024, K=512)
    gemm_bt<3, 64, 128><<<dim3(8, 8, BATCH), 256, 0, stream>>>(
        wp_b, 0, 512, O1T, 524288, 512, 512,
        out, 524288, 1024, bproj, x, nullptr, nullptr, 0.f);
}